// Round 2
// baseline (472.517 us; speedup 1.0000x reference)
//
#include <hip/hip_runtime.h>
#include <math.h>

#define N_POS 8192
#define BATCH 4
#define N_GT 512
#define BG (BATCH * N_GT)        // 2048 flattened (b,g) columns
#define EPSV 1e-6f

// workspace layout (float offsets)
#define WS_DPACK 0               // [8192][2048] packed gathered columns (64 MiB)
#define WS_PARTS 16777216        // [1024][2048] kC partial sums (8 MiB)
#define WS_MIND  18874368        // [4][8192] min_g D per (b,n)
#define WS_PMAX  18907136        // [1024] kA block maxes
#define WS_SC    18908160        // [0]=maxd [1]=pmin [2]=prange [3..6]=n_est [7..10]=t1 [11]=t2sum

#define KA_BLOCKS 1024
#define ROWS_A 8
#define KC_BLOCKS 1024
#define ROWS_C 8

// ---------------- kA: single pass over dis_matrix ----------------
// computes global max partials, packs gathered columns to Dpack, per-(b,n) min -> minD
__global__ __launch_bounds__(256) void whd_kA(const float* __restrict__ dis,
                                              const int* __restrict__ gt,
                                              float* __restrict__ wsf) {
    __shared__ float rowbuf[N_POS];     // 32 KB
    __shared__ unsigned short gtl[BG];  // 4 KB (indices < 8192 fit in u16)
    __shared__ float minsh[4][4];       // [wave][batch]
    __shared__ float smax[4];
    int t = threadIdx.x;
    int wv = t >> 6, lane = t & 63;
    int row0 = blockIdx.x * ROWS_A;
    float* dpack = wsf + WS_DPACK;
    float* minD = wsf + WS_MIND;

    for (int i = t; i < BG; i += 256) gtl[i] = (unsigned short)gt[i];
    __syncthreads();
    int c[8];
    #pragma unroll
    for (int k = 0; k < 8; k++) c[k] = gtl[t + 256 * k];

    float tmax = -INFINITY;
    for (int r = 0; r < ROWS_A; r++) {
        int n = row0 + r;
        if (r > 0) {
            __syncthreads();            // rowbuf from row r-1 fully consumed; minsh(r-1) visible
            if (t < BATCH) {            // finalize minD for previous row
                float m = fminf(fminf(minsh[0][t], minsh[1][t]), fminf(minsh[2][t], minsh[3][t]));
                minD[t * N_POS + (n - 1)] = m;
            }
        }
        // stage row -> LDS, fold into running max from registers
        const float4* src = (const float4*)(dis + (size_t)n * N_POS);
        float4* dstl = (float4*)rowbuf;
        #pragma unroll
        for (int j = 0; j < N_POS / 4 / 256; j++) {
            int i = t + 256 * j;
            float4 v = src[i];
            tmax = fmaxf(tmax, fmaxf(fmaxf(v.x, v.y), fmaxf(v.z, v.w)));
            dstl[i] = v;
        }
        __syncthreads();
        // gather + pack + per-batch min
        float vmin[4];
        #pragma unroll
        for (int k = 0; k < 8; k++) {
            float v = rowbuf[c[k]];
            dpack[(size_t)n * BG + t + 256 * k] = v;
            int b = k >> 1;
            if ((k & 1) == 0) vmin[b] = v; else vmin[b] = fminf(vmin[b], v);
        }
        #pragma unroll
        for (int b = 0; b < BATCH; b++) {
            float m = vmin[b];
            #pragma unroll
            for (int off = 32; off; off >>= 1) m = fminf(m, __shfl_xor(m, off, 64));
            if (lane == 0) minsh[wv][b] = m;
        }
    }
    __syncthreads();
    if (t < BATCH) {
        float m = fminf(fminf(minsh[0][t], minsh[1][t]), fminf(minsh[2][t], minsh[3][t]));
        minD[t * N_POS + (row0 + ROWS_A - 1)] = m;
    }
    // block max reduction
    #pragma unroll
    for (int off = 32; off; off >>= 1) tmax = fmaxf(tmax, __shfl_down(tmax, off, 64));
    if (lane == 0) smax[wv] = tmax;
    __syncthreads();
    if (t == 0)
        wsf[WS_PMAX + blockIdx.x] = fmaxf(fmaxf(smax[0], smax[1]), fmaxf(smax[2], smax[3]));
}

// ---------------- kB1: finalize scalars, zero accumulators ----------------
__global__ __launch_bounds__(1024) void whd_kB1(const float* __restrict__ prob,
                                                float* __restrict__ wsf) {
    __shared__ float red[1024];
    int t = threadIdx.x;
    float m = -INFINITY;
    for (int i = t; i < KA_BLOCKS; i += 1024) m = fmaxf(m, wsf[WS_PMAX + i]);
    red[t] = m; __syncthreads();
    for (int s = 512; s; s >>= 1) { if (t < s) red[t] = fmaxf(red[t], red[t + s]); __syncthreads(); }
    float maxdist = red[0]; __syncthreads();
    float lmin = INFINITY, lmax = -INFINITY;
    for (int i = t; i < BATCH * N_POS; i += 1024) {
        float v = prob[i];
        lmin = fminf(lmin, v); lmax = fmaxf(lmax, v);
    }
    red[t] = lmin; __syncthreads();
    for (int s = 512; s; s >>= 1) { if (t < s) red[t] = fminf(red[t], red[t + s]); __syncthreads(); }
    float pmin = red[0]; __syncthreads();
    red[t] = lmax; __syncthreads();
    for (int s = 512; s; s >>= 1) { if (t < s) red[t] = fmaxf(red[t], red[t + s]); __syncthreads(); }
    float pmax = red[0];
    if (t == 0) {
        wsf[WS_SC + 0] = maxdist;
        wsf[WS_SC + 1] = pmin;
        wsf[WS_SC + 2] = pmax - pmin;
    }
    if (t >= 3 && t < 12) wsf[WS_SC + t] = 0.f;  // zero n_est[4], t1[4], t2sum
}

// ---------------- kB2: n_est and term1 partials ----------------
__global__ __launch_bounds__(128) void whd_kB2(const float* __restrict__ prob,
                                               float* __restrict__ wsf) {
    __shared__ float sred[2];
    int t = threadIdx.x;
    int n = blockIdx.x * 128 + t;
    float pmin = wsf[WS_SC + 1];
    float invr = 1.0f / wsf[WS_SC + 2];
    const float* minD = wsf + WS_MIND;
    #pragma unroll
    for (int b = 0; b < BATCH; b++) {
        float p = (prob[b * N_POS + n] - pmin) * invr;
        p = fminf(fmaxf(p, 0.f), 1.f);
        float pm = p * minD[b * N_POS + n];
        #pragma unroll
        for (int off = 32; off; off >>= 1) {
            p += __shfl_down(p, off, 64);
            pm += __shfl_down(pm, off, 64);
        }
        if ((t & 63) == 0) { if (t == 64) { sred[0] = p; sred[1] = pm; } }
        __syncthreads();
        if (t == 0) {
            atomicAdd(&wsf[WS_SC + 3 + b], p + sred[0]);
            atomicAdd(&wsf[WS_SC + 7 + b], pm + sred[1]);
        }
        __syncthreads();
    }
}

// ---------------- kC: reciprocal pass over packed columns ----------------
__global__ __launch_bounds__(256) void whd_kC(const float* __restrict__ prob,
                                              float* __restrict__ wsf) {
    int t = threadIdx.x;
    int row0 = blockIdx.x * ROWS_C;
    const float* dpack = wsf + WS_DPACK;
    float maxd = wsf[WS_SC + 0];
    float pmin = wsf[WS_SC + 1];
    float invr = 1.0f / wsf[WS_SC + 2];
    float acc[8];
    #pragma unroll
    for (int k = 0; k < 8; k++) acc[k] = 0.f;
    for (int r = 0; r < ROWS_C; r++) {
        int n = row0 + r;
        float pb[4];
        #pragma unroll
        for (int b = 0; b < BATCH; b++) {
            float p = (prob[b * N_POS + n] - pmin) * invr;
            pb[b] = fminf(fmaxf(p, 0.f), 1.f);
        }
        const float* rowp = dpack + (size_t)n * BG;
        #pragma unroll
        for (int k = 0; k < 8; k++) {
            float d = rowp[t + 256 * k];
            float w = fmaf(pb[k >> 1], d - maxd, maxd) + EPSV;  // (1-p)*M + p*d + eps
            acc[k] += 1.0f / w;
        }
    }
    float* outp = wsf + WS_PARTS + (size_t)blockIdx.x * BG;
    #pragma unroll
    for (int k = 0; k < 8; k++) outp[t + 256 * k] = acc[k];
}

// ---------------- kD: reduce partials -> term2 sum ----------------
__global__ __launch_bounds__(256) void whd_kD(float* __restrict__ wsf) {
    __shared__ float red[256];
    int t = threadIdx.x;
    int col = blockIdx.x * 256 + t;
    const float* parts = wsf + WS_PARTS;
    float s = 0.f;
    for (int ch = 0; ch < KC_BLOCKS; ch++) s += parts[(size_t)ch * BG + col];
    float val = (float)N_POS / s;   // (mean_n (w+eps)^-1)^-1 = N/S
    red[t] = val; __syncthreads();
    for (int st = 128; st; st >>= 1) { if (t < st) red[t] += red[t + st]; __syncthreads(); }
    if (t == 0) atomicAdd(&wsf[WS_SC + 11], red[0]);
}

// ---------------- kE: final scalar ----------------
__global__ __launch_bounds__(64) void whd_kE(const float* __restrict__ wsf,
                                             float* __restrict__ out) {
    if (threadIdx.x == 0) {
        float term1 = 0.f;
        for (int b = 0; b < BATCH; b++)
            term1 += wsf[WS_SC + 7 + b] / (wsf[WS_SC + 3 + b] + EPSV);
        term1 *= (1.0f / BATCH);
        float term2 = wsf[WS_SC + 11] * (1.0f / BG);
        out[0] = term1 + term2;
    }
}

extern "C" void kernel_launch(void* const* d_in, const int* in_sizes, int n_in,
                              void* d_out, int out_size, void* d_ws, size_t ws_size,
                              hipStream_t stream) {
    const float* prob = (const float*)d_in[0];       // (4, 8192) fp32
    const int* gt = (const int*)d_in[1];             // (4, 512) int32
    const float* dis = (const float*)d_in[2];        // (8192, 8192) fp32
    float* out = (float*)d_out;
    float* wsf = (float*)d_ws;

    whd_kA<<<KA_BLOCKS, 256, 0, stream>>>(dis, gt, wsf);
    whd_kB1<<<1, 1024, 0, stream>>>(prob, wsf);
    whd_kB2<<<N_POS / 128, 128, 0, stream>>>(prob, wsf);
    whd_kC<<<KC_BLOCKS, 256, 0, stream>>>(prob, wsf);
    whd_kD<<<BG / 256, 256, 0, stream>>>(wsf);
    whd_kE<<<1, 64, 0, stream>>>(wsf, out);
}